// Round 7
// baseline (196.235 us; speedup 1.0000x reference)
//
#include <hip/hip_runtime.h>
#include <hip/hip_bf16.h>
#include <math.h>

#define NB 32
#define NR 512
#define NT 128

typedef __attribute__((ext_vector_type(8))) short short8;
typedef __attribute__((ext_vector_type(4))) float f32x4;
typedef __attribute__((ext_vector_type(2))) float f32x2;

// ---------------- wave (64-lane) reductions ----------------
#define DPPF(s, ctrl) \
  __int_as_float(__builtin_amdgcn_update_dpp(0, __float_as_int(s), ctrl, 0xf, 0xf, true))

__device__ __forceinline__ float wred_max(float v){
  v = fmaxf(v, DPPF(v, 0xB1));
  v = fmaxf(v, DPPF(v, 0x4E));
  v = fmaxf(v, DPPF(v, 0x141));
  v = fmaxf(v, DPPF(v, 0x140));
  v = fmaxf(v, __shfl_xor(v, 16));
  v = fmaxf(v, __shfl_xor(v, 32));
  return v;
}
__device__ __forceinline__ float wred_sum(float v){
  v += DPPF(v, 0xB1);
  v += DPPF(v, 0x4E);
  v += DPPF(v, 0x141);
  v += DPPF(v, 0x140);
  v += __shfl_xor(v, 16);
  v += __shfl_xor(v, 32);
  return v;
}

// packed (f32x2) variants: 2 values per op via v_pk_*
__device__ __forceinline__ f32x2 wred_max2(f32x2 v){
  f32x2 t;
  t.x = DPPF(v.x, 0xB1);  t.y = DPPF(v.y, 0xB1);  v = __builtin_elementwise_max(v, t);
  t.x = DPPF(v.x, 0x4E);  t.y = DPPF(v.y, 0x4E);  v = __builtin_elementwise_max(v, t);
  t.x = DPPF(v.x, 0x141); t.y = DPPF(v.y, 0x141); v = __builtin_elementwise_max(v, t);
  t.x = DPPF(v.x, 0x140); t.y = DPPF(v.y, 0x140); v = __builtin_elementwise_max(v, t);
  t.x = __shfl_xor(v.x, 16); t.y = __shfl_xor(v.y, 16); v = __builtin_elementwise_max(v, t);
  t.x = __shfl_xor(v.x, 32); t.y = __shfl_xor(v.y, 32); v = __builtin_elementwise_max(v, t);
  return v;
}
__device__ __forceinline__ f32x2 wred_sum2(f32x2 v){
  f32x2 t;
  t.x = DPPF(v.x, 0xB1);  t.y = DPPF(v.y, 0xB1);  v += t;
  t.x = DPPF(v.x, 0x4E);  t.y = DPPF(v.y, 0x4E);  v += t;
  t.x = DPPF(v.x, 0x141); t.y = DPPF(v.y, 0x141); v += t;
  t.x = DPPF(v.x, 0x140); t.y = DPPF(v.y, 0x140); v += t;
  t.x = __shfl_xor(v.x, 16); t.y = __shfl_xor(v.y, 16); v += t;
  t.x = __shfl_xor(v.x, 32); t.y = __shfl_xor(v.y, 32); v += t;
  return v;
}

// packed 16-lane-group sum (2 robots per chain). Result in n16==15.
__device__ __forceinline__ f32x2 dpp_add16_pk(f32x2 s){
  f32x2 t;
  t.x = DPPF(s.x, 0x111); t.y = DPPF(s.y, 0x111); s += t;   // row_shr:1
  t.x = DPPF(s.x, 0x112); t.y = DPPF(s.y, 0x112); s += t;   // row_shr:2
  t.x = DPPF(s.x, 0x114); t.y = DPPF(s.y, 0x114); s += t;   // row_shr:4
  t.x = DPPF(s.x, 0x118); t.y = DPPF(s.y, 0x118); s += t;   // row_shr:8
  return s;
}

// ---------------- encoder kernel (641 blocks, unchanged) ----------------
__global__ __launch_bounds__(256) void enc_kernel(
    const float* __restrict__ rs, const float* __restrict__ ts,
    const float* __restrict__ r_w1, const float* __restrict__ r_b1,
    const float* __restrict__ r_w2, const float* __restrict__ r_b2,
    const float* __restrict__ t_w1, const float* __restrict__ t_b1,
    const float* __restrict__ t_w2, const float* __restrict__ t_b2,
    const float* __restrict__ wq, const float* __restrict__ bq,
    const float* __restrict__ wk, const float* __restrict__ bk,
    const float* __restrict__ wv, const float* __restrict__ bv,
    const float* __restrict__ a_w1, const float* __restrict__ a_w2,
    const float* __restrict__ wo, const float* __restrict__ bo,
    const float* __restrict__ a_b1,
    float* __restrict__ kbuf, float* __restrict__ vbuf,
    float* __restrict__ rpbuf, float* __restrict__ qbuf,
    unsigned short* __restrict__ w2f,
    float* __restrict__ wfuse, float* __restrict__ bfuse)
{
  __shared__ float w1s[448];
  __shared__ float wss[4096];
  __shared__ float h_s[32 * 66];
  __shared__ float rf_s[32 * 66];

  const int tid = threadIdx.x;
  const int blk = blockIdx.x;

  if (blk == 640) {        // fused prep block
#pragma unroll
    for (int c = 0; c < 4; ++c)
      ((float4*)wss)[c * 256 + tid] = ((const float4*)wo)[c * 256 + tid];

    // split a_w2 into hi/lo bf16 B-frags
    if (tid < 64) {
      int l = tid, n16 = l & 15, g = l >> 4;
      for (int f = 0; f < 8; ++f) {
        int ntile = f & 1, ks = (f >> 1) & 1, part = f >> 2;
        for (int j = 0; j < 8; ++j) {
          int k = ks * 32 + g * 8 + j;
          int n = ntile * 16 + n16;
          unsigned wb = __float_as_uint(a_w2[k * 32 + n]);
          unsigned hib = wb & 0xffff0000u;
          float lof = __uint_as_float(wb) - __uint_as_float(hib);
          unsigned lob = __float_as_uint(lof) & 0xffff0000u;
          w2f[((size_t)f * 64 + l) * 8 + j] =
              (unsigned short)((part == 0 ? hib : lob) >> 16);
        }
      }
    }
    __syncthreads();

    // wfuse = wo @ a_w1[:64]  (64x64) -- D/E linear collapse (no relu between)
    {
      const int j = tid & 63, kg = tid >> 6;
      float acc[16];
#pragma unroll
      for (int kk = 0; kk < 16; ++kk) acc[kk] = 0.f;
      for (int m = 0; m < 64; ++m) {
        float aw = a_w1[m * 64 + j];
#pragma unroll
        for (int kk = 0; kk < 16; ++kk)
          acc[kk] += wss[(kg * 16 + kk) * 64 + m] * aw;
      }
#pragma unroll
      for (int kk = 0; kk < 16; ++kk)
        wfuse[(kg * 16 + kk) * 64 + j] = acc[kk];
    }
    // bfuse = bo @ a_w1[:64] + a_b1
    if (tid < 64) {
      float acc = a_b1[tid];
      for (int m = 0; m < 64; ++m) acc += bo[m] * a_w1[m * 64 + tid];
      bfuse[tid] = acc;
    }
    return;
  }

  const int rb = tid >> 3, t8 = tid & 7;
  const bool robot = blk < 512;

  if (robot) {
    if (tid < 112) ((float4*)w1s)[tid] = ((const float4*)r_w1)[tid];
#pragma unroll
    for (int c = 0; c < 4; ++c)
      ((float4*)wss)[c * 256 + tid] = ((const float4*)r_w2)[c * 256 + tid];
  } else {
    if (tid < 96) ((float4*)w1s)[tid] = ((const float4*)t_w1)[tid];
#pragma unroll
    for (int c = 0; c < 4; ++c)
      ((float4*)wss)[c * 256 + tid] = ((const float4*)t_w2)[c * 256 + tid];
  }

  int g, K1;
  const float* xin; const float* b1; const float* b2;
  if (robot) { g = blk * 32 + rb;          K1 = 7; xin = rs + (size_t)g * 7; b1 = r_b1; b2 = r_b2; }
  else       { g = (blk - 512) * 32 + rb;  K1 = 6; xin = ts + (size_t)g * 6; b1 = t_b1; b2 = t_b2; }

  float x[7];
  for (int k = 0; k < K1; ++k) x[k] = xin[k];
  __syncthreads();

  {
    float acc[8];
#pragma unroll
    for (int jj = 0; jj < 8; ++jj) acc[jj] = b1[t8 * 8 + jj];
    for (int k = 0; k < K1; ++k) {
      float xv = x[k];
#pragma unroll
      for (int jj = 0; jj < 8; ++jj) acc[jj] += xv * w1s[k * 64 + t8 * 8 + jj];
    }
#pragma unroll
    for (int jj = 0; jj < 8; ++jj) h_s[rb * 66 + t8 * 8 + jj] = fmaxf(acc[jj], 0.f);
  }
  __syncthreads();

  {
    float acc[8];
#pragma unroll
    for (int jj = 0; jj < 8; ++jj) acc[jj] = b2[t8 * 8 + jj];
    for (int k = 0; k < 64; ++k) {
      float hv = h_s[rb * 66 + k];
      const float4* wr = (const float4*)(wss + k * 64 + t8 * 8);
#pragma unroll
      for (int j4 = 0; j4 < 2; ++j4) {
        float4 w = wr[j4];
        acc[j4 * 4 + 0] += hv * w.x; acc[j4 * 4 + 1] += hv * w.y;
        acc[j4 * 4 + 2] += hv * w.z; acc[j4 * 4 + 3] += hv * w.w;
      }
    }
#pragma unroll
    for (int jj = 0; jj < 8; ++jj) rf_s[rb * 66 + t8 * 8 + jj] = fmaxf(acc[jj], 0.f);
  }

  const float* wp[3]; const float* bp[3]; float* op[3]; int npass;
  if (robot) {
    wp[0] = wk; bp[0] = bk;      op[0] = kbuf;
    wp[1] = wv; bp[1] = bv;      op[1] = vbuf;
    wp[2] = a_w1 + 64 * 64; bp[2] = nullptr; op[2] = rpbuf;
    npass = 3;
  } else {
    wp[0] = wq; bp[0] = bq; op[0] = qbuf; npass = 1;
  }
  for (int p = 0; p < npass; ++p) {
    __syncthreads();
#pragma unroll
    for (int c = 0; c < 4; ++c)
      ((float4*)wss)[c * 256 + tid] = ((const float4*)wp[p])[c * 256 + tid];
    __syncthreads();
    float acc[8];
#pragma unroll
    for (int jj = 0; jj < 8; ++jj) acc[jj] = bp[p] ? bp[p][t8 * 8 + jj] : 0.f;
    for (int k = 0; k < 64; ++k) {
      float hv = rf_s[rb * 66 + k];
      const float4* wr = (const float4*)(wss + k * 64 + t8 * 8);
#pragma unroll
      for (int j4 = 0; j4 < 2; ++j4) {
        float4 w = wr[j4];
        acc[j4 * 4 + 0] += hv * w.x; acc[j4 * 4 + 1] += hv * w.y;
        acc[j4 * 4 + 2] += hv * w.z; acc[j4 * 4 + 3] += hv * w.w;
      }
    }
    float4* o4 = (float4*)(op[p] + (size_t)g * 64 + t8 * 8);
    o4[0] = make_float4(acc[0], acc[1], acc[2], acc[3]);
    o4[1] = make_float4(acc[4], acc[5], acc[6], acc[7]);
  }
}

// ---------------- split helpers (pair) -------------------------------------
// hi/lo bf16 split via HW v_cvt_pk_bf16_f32 (1 instr vs HIP's software RNE).
// Residual algebra unchanged: hi = bf16(x); e = x - hi (exact); lo = bf16(e).
__device__ __forceinline__ void mk2(f32x2 r, f32x2 t,
                                    unsigned* h, unsigned* l)
{
  f32x2 x = r + t;                                     // v_pk_add_f32
  x = __builtin_elementwise_max(x, (f32x2){0.f, 0.f}); // v_pk_max_f32
  unsigned hh;
  asm("v_cvt_pk_bf16_f32 %0, %1, %2" : "=v"(hh) : "v"(x.x), "v"(x.y));
  f32x2 hf;
  hf.x = __int_as_float((int)(hh << 16));
  hf.y = __int_as_float((int)(hh & 0xffff0000u));
  f32x2 e = x - hf;                                    // exact residual
  unsigned ll;
  asm("v_cvt_pk_bf16_f32 %0, %1, %2" : "=v"(ll) : "v"(e.x), "v"(e.y));
  *h = hh; *l = ll;
}

__device__ __forceinline__ void mk_frags(float4 ra, float4 rb,
                                         float4 ta, float4 tb,
                                         short8* Ah, short8* Al)
{
  unsigned h0, h1, h2, h3, l0, l1, l2, l3;
  mk2((f32x2){ra.x, ra.y}, (f32x2){ta.x, ta.y}, &h0, &l0);
  mk2((f32x2){ra.z, ra.w}, (f32x2){ta.z, ta.w}, &h1, &l1);
  mk2((f32x2){rb.x, rb.y}, (f32x2){tb.x, tb.y}, &h2, &l2);
  mk2((f32x2){rb.z, rb.w}, (f32x2){tb.z, tb.w}, &h3, &l3);
  *Ah = __builtin_bit_cast(short8, make_int4((int)h0, (int)h1, (int)h2, (int)h3));
  *Al = __builtin_bit_cast(short8, make_int4((int)l0, (int)l1, (int)l2, (int)l3));
}

// ---------------- fused attention + pairwise kernel ------------------------
// v13 = v12 + (a) HW cvt_pk_bf16 in mk2, (b) cp[] aliased into dead lg region
// (LDS 20480 -> ~18432 B: guarantees 8 blocks/CU even with driver-reserved
// LDS). Everything else byte-identical to v12.
__global__ __launch_bounds__(256, 4) void attn_pair_kernel(
    const float* __restrict__ qbuf, const float* __restrict__ kbuf,
    const float* __restrict__ vbuf,
    const float* __restrict__ wfuse, const float* __restrict__ bfuse,
    const unsigned short* __restrict__ w2f,
    const float* __restrict__ a_b2, const float* __restrict__ a_w3,
    const float* __restrict__ rpbuf,
    float* __restrict__ out)
{
  __shared__ float qt_s[2 * 64];        // q in phase A
  __shared__ float lg[4160];            // p pairs A-C; ctx partials; cp; scores
  __shared__ float inv_s[8];
  __shared__ float ctx_s[2 * 64];
  __shared__ float tp_f[2 * 64];
  __shared__ float red_a[4];
  __shared__ float red_b[4];

  float* const lgf = lg;
  float* const cpf = lg + 2624;         // cp alias: live only in phase D;
                                        // ctx partials end at 2108, scores at 1024

  const int tid = threadIdx.x;
  const int jj = blockIdx.x & 31;
  const int b  = (jj & 7) * 4 + (jj >> 3);   // XCD-locality swizzle
  const int t0 = (blockIdx.x >> 5) * 2;      // 64 task-pairs

  // ---------- attn phase A: logits ----------
  if (tid < 32) {
    int tt = tid >> 4, i4 = tid & 15;
    float4 v = ((const float4*)(qbuf + (size_t)(b * NT + t0 + tt) * 64))[i4];
    v.x *= 0.25f; v.y *= 0.25f; v.z *= 0.25f; v.w *= 0.25f;   // 1/sqrt(16)
    ((float4*)qt_s)[tid] = v;
  }
  __syncthreads();

  {
    const int h = tid & 3;
    const int r0 = tid >> 2;
    const f32x4* q0p = (const f32x4*)(qt_s + h * 16);
    const f32x4* q1p = (const f32x4*)(qt_s + 64 + h * 16);
    f32x2 q0[8], q1[8];
#pragma unroll
    for (int j = 0; j < 4; ++j) {
      f32x4 a = q0p[j], c = q1p[j];
      q0[2 * j]     = __builtin_shufflevector(a, a, 0, 1);
      q0[2 * j + 1] = __builtin_shufflevector(a, a, 2, 3);
      q1[2 * j]     = __builtin_shufflevector(c, c, 0, 1);
      q1[2 * j + 1] = __builtin_shufflevector(c, c, 2, 3);
    }
    const float* kb0 = kbuf + (size_t)b * NR * 64 + h * 16;
    for (int it = 0; it < 8; ++it) {
      int r = r0 + it * 64;
      const f32x4* k4 = (const f32x4*)(kb0 + (size_t)r * 64);
      f32x2 a0 = {0.f, 0.f}, a1 = {0.f, 0.f};
#pragma unroll
      for (int j = 0; j < 4; ++j) {
        f32x4 kv = k4[j];
        f32x2 kl = __builtin_shufflevector(kv, kv, 0, 1);
        f32x2 kh = __builtin_shufflevector(kv, kv, 2, 3);
        a0 = __builtin_elementwise_fma(kl, q0[2 * j], a0);
        a0 = __builtin_elementwise_fma(kh, q0[2 * j + 1], a0);
        a1 = __builtin_elementwise_fma(kl, q1[2 * j], a1);
        a1 = __builtin_elementwise_fma(kh, q1[2 * j + 1], a1);
      }
      *(f32x2*)(lgf + h * 1040 + r * 2) = (f32x2){a0.x + a0.y, a1.x + a1.y};
    }
  }
  __syncthreads();

  // ---------- attn phase B: softmax, both tasks per row (packed) ----------
  {
    const int hh = tid >> 6, lane = tid & 63;
    float* row = lgf + hh * 1040;
    f32x2 v0[8];
#pragma unroll
    for (int u = 0; u < 8; ++u) v0[u] = *(const f32x2*)(row + (u * 64 + lane) * 2);
    f32x2 m = v0[0];
#pragma unroll
    for (int u = 1; u < 8; ++u) m = __builtin_elementwise_max(m, v0[u]);
    m = wred_max2(m);
    f32x2 s = {0.f, 0.f};
#pragma unroll
    for (int u = 0; u < 8; ++u) {
      f32x2 e;
      e.x = __expf(v0[u].x - m.x);
      e.y = __expf(v0[u].y - m.y);
      *(f32x2*)(row + (u * 64 + lane) * 2) = e;
      s += e;
    }
    s = wred_sum2(s);
    if (lane == 0) {
      inv_s[hh]     = __builtin_amdgcn_rcpf(s.x);
      inv_s[4 + hh] = __builtin_amdgcn_rcpf(s.y);
    }
  }
  __syncthreads();

  // ---------- attn phase C: ctx = p.v (b128 p-pairs, pk-FMA) ----------
  {
    const int dg = tid & 15, rc = tid >> 4;
    const int h = dg >> 2;
    const float* vptr = vbuf + (size_t)b * NR * 64 + dg * 4;
    const float* pr = lgf + h * 1040 + rc * 64;     // r = rc*32 + i
    f32x4 acc0 = {0.f, 0.f, 0.f, 0.f}, acc1 = {0.f, 0.f, 0.f, 0.f};
#pragma unroll 8
    for (int i = 0; i < 32; i += 2) {
      int r = rc * 32 + i;
      f32x4 vv0 = *(const f32x4*)(vptr + (size_t)r * 64);
      f32x4 vv1 = *(const f32x4*)(vptr + (size_t)(r + 1) * 64);
      f32x4 pp = *(const f32x4*)(pr + i * 2);        // p0[i],p1[i],p0[i+1],p1[i+1]
      acc0 = __builtin_elementwise_fma(vv0, (f32x4){pp.x, pp.x, pp.x, pp.x}, acc0);
      acc1 = __builtin_elementwise_fma(vv0, (f32x4){pp.y, pp.y, pp.y, pp.y}, acc1);
      acc0 = __builtin_elementwise_fma(vv1, (f32x4){pp.z, pp.z, pp.z, pp.z}, acc0);
      acc1 = __builtin_elementwise_fma(vv1, (f32x4){pp.w, pp.w, pp.w, pp.w}, acc1);
    }
    __syncthreads();                               // all p reads complete
    *(f32x4*)(lgf + rc * 132 + dg * 4)      = acc0;
    *(f32x4*)(lgf + rc * 132 + 64 + dg * 4) = acc1;
  }
  __syncthreads();
  if (tid < 128) {
    float s = 0.f;
#pragma unroll
    for (int rc = 0; rc < 16; ++rc) s += lgf[rc * 132 + tid];
    ctx_s[tid] = s * inv_s[(tid >> 6) * 4 + ((tid & 63) >> 4)];
  }
  __syncthreads();

  // ---------- fused D+E: tp = ctx @ wfuse + bfuse ----------
  {
    int jd = tid & 63, kc = tid >> 6;
    float p0 = 0.f, p1 = 0.f;
    for (int k = 0; k < 16; ++k) {
      float w = wfuse[(kc * 16 + k) * 64 + jd];
      p0 += ctx_s[kc * 16 + k] * w;
      p1 += ctx_s[64 + kc * 16 + k] * w;
    }
    cpf[kc * 128 + jd]      = p0;
    cpf[kc * 128 + 64 + jd] = p1;
  }
  __syncthreads();
  if (tid < 128) {
    tp_f[tid] = cpf[tid] + cpf[128 + tid] + cpf[256 + tid] + cpf[384 + tid] +
                bfuse[tid & 63];
  }
  __syncthreads();

  // ---------- pair body (MFMA sequence v12-identical; packed epilogue) ------
  const int wave = tid >> 6, lane = tid & 63;
  const int n16 = lane & 15, g = lane >> 4;

  short8 B[8];
#pragma unroll
  for (int f = 0; f < 8; ++f)
    B[f] = __builtin_bit_cast(short8, ((const int4*)w2f)[f * 64 + lane]);

  const float* tpA = tp_f + g * 8;
  const float* tpB = tp_f + 64 + g * 8;
  float4 tA0a = *(const float4*)(tpA),      tA0b = *(const float4*)(tpA + 4);
  float4 tA1a = *(const float4*)(tpA + 32), tA1b = *(const float4*)(tpA + 36);
  float4 tB0a = *(const float4*)(tpB),      tB0b = *(const float4*)(tpB + 4);
  float4 tB1a = *(const float4*)(tpB + 32), tB1b = *(const float4*)(tpB + 36);

  float b20 = a_b2[n16], b21 = a_b2[16 + n16];
  float w30 = a_w3[n16], w31 = a_w3[16 + n16];

  const float* rpb = rpbuf + (size_t)b * NR * 64 + g * 8;

  const float4* rp0 = (const float4*)(rpb + (size_t)(wave * 128 + n16) * 64);
  float4 ra0 = rp0[0], rb0 = rp0[1], ra1 = rp0[8], rb1 = rp0[9];

#pragma unroll
  for (int mt = 0; mt < 8; ++mt) {
    float4 na0, nb0, na1, nb1;
    if (mt < 7) {
      const float4* rpn =
          (const float4*)(rpb + (size_t)(wave * 128 + (mt + 1) * 16 + n16) * 64);
      na0 = rpn[0]; nb0 = rpn[1]; na1 = rpn[8]; nb1 = rpn[9];
    }

#pragma unroll
    for (int task = 0; task < 2; ++task) {
      short8 Ah0, Al0, Ah1, Al1;
      if (task == 0) {
        mk_frags(ra0, rb0, tA0a, tA0b, &Ah0, &Al0);
        mk_frags(ra1, rb1, tA1a, tA1b, &Ah1, &Al1);
      } else {
        mk_frags(ra0, rb0, tB0a, tB0b, &Ah0, &Al0);
        mk_frags(ra1, rb1, tB1a, tB1b, &Ah1, &Al1);
      }
      f32x4 acc0 = (f32x4){b20, b20, b20, b20};
      f32x4 acc1 = (f32x4){b21, b21, b21, b21};
      acc0 = __builtin_amdgcn_mfma_f32_16x16x32_bf16(Ah0, B[0], acc0, 0, 0, 0);
      acc1 = __builtin_amdgcn_mfma_f32_16x16x32_bf16(Ah0, B[1], acc1, 0, 0, 0);
      acc0 = __builtin_amdgcn_mfma_f32_16x16x32_bf16(Al0, B[0], acc0, 0, 0, 0);
      acc1 = __builtin_amdgcn_mfma_f32_16x16x32_bf16(Al0, B[1], acc1, 0, 0, 0);
      acc0 = __builtin_amdgcn_mfma_f32_16x16x32_bf16(Ah0, B[4], acc0, 0, 0, 0);
      acc1 = __builtin_amdgcn_mfma_f32_16x16x32_bf16(Ah0, B[5], acc1, 0, 0, 0);
      acc0 = __builtin_amdgcn_mfma_f32_16x16x32_bf16(Ah1, B[2], acc0, 0, 0, 0);
      acc1 = __builtin_amdgcn_mfma_f32_16x16x32_bf16(Ah1, B[3], acc1, 0, 0, 0);
      acc0 = __builtin_amdgcn_mfma_f32_16x16x32_bf16(Al1, B[2], acc0, 0, 0, 0);
      acc1 = __builtin_amdgcn_mfma_f32_16x16x32_bf16(Al1, B[3], acc1, 0, 0, 0);
      acc0 = __builtin_amdgcn_mfma_f32_16x16x32_bf16(Ah1, B[6], acc0, 0, 0, 0);
      acc1 = __builtin_amdgcn_mfma_f32_16x16x32_bf16(Ah1, B[7], acc1, 0, 0, 0);
      // packed epilogue: robots (reg0,reg1) and (reg2,reg3) as f32x2
      {
        f32x2 z = {0.f, 0.f};
        f32x2 w30v = {w30, w30}, w31v = {w31, w31};
        f32x2 m01 = __builtin_elementwise_max(
            (f32x2){acc0[0], acc0[1]}, z);
        f32x2 m23 = __builtin_elementwise_max(
            (f32x2){acc0[2], acc0[3]}, z);
        f32x2 n01 = __builtin_elementwise_max(
            (f32x2){acc1[0], acc1[1]}, z);
        f32x2 n23 = __builtin_elementwise_max(
            (f32x2){acc1[2], acc1[3]}, z);
        f32x2 s01 = __builtin_elementwise_fma(n01, w31v, m01 * w30v);
        f32x2 s23 = __builtin_elementwise_fma(n23, w31v, m23 * w30v);
        s01 = dpp_add16_pk(s01);
        s23 = dpp_add16_pk(s23);
        if (n16 == 15) {
          float* dst = lgf + task * 512 + wave * 128 + mt * 16 + g * 4;
          *(f32x2*)(dst)     = s01;
          *(f32x2*)(dst + 2) = s23;
        }
      }
    }
    ra0 = na0; rb0 = nb0; ra1 = na1; rb1 = nb1;
  }
  __syncthreads();

  // ---------- softmax over 512 robots, 128 threads per task ----------
  {
    const int task = tid >> 7, t2 = tid & 127;
    const int lw = tid & 63, wid = tid >> 6;
    const float* pp = lgf + task * 512;
    float v0 = pp[t2], v1 = pp[t2 + 128], v2 = pp[t2 + 256], v3 = pp[t2 + 384];
    float m = wred_max(fmaxf(fmaxf(v0, v1), fmaxf(v2, v3)));
    if (lw == 0) red_a[wid] = m;
    __syncthreads();
    m = fmaxf(red_a[task * 2], red_a[task * 2 + 1]);
    float e0 = __expf(v0 - m), e1 = __expf(v1 - m);
    float e2 = __expf(v2 - m), e3 = __expf(v3 - m);
    float ss = wred_sum((e0 + e1) + (e2 + e3));
    if (lw == 0) red_b[wid] = ss;
    __syncthreads();
    float inv = __builtin_amdgcn_rcpf(red_b[task * 2] + red_b[task * 2 + 1]);
    float* op = out + (size_t)(b * NT + t0 + task) * NR;
    op[t2]       = e0 * inv;
    op[t2 + 128] = e1 * inv;
    op[t2 + 256] = e2 * inv;
    op[t2 + 384] = e3 * inv;
  }
}

// ---------------- launch ----------------
extern "C" void kernel_launch(void* const* d_in, const int* in_sizes, int n_in,
                              void* d_out, int out_size, void* d_ws, size_t ws_size,
                              hipStream_t stream)
{
  const float* rs   = (const float*)d_in[0];
  const float* ts   = (const float*)d_in[1];
  const float* r_w1 = (const float*)d_in[2];  const float* r_b1 = (const float*)d_in[3];
  const float* r_w2 = (const float*)d_in[4];  const float* r_b2 = (const float*)d_in[5];
  const float* t_w1 = (const float*)d_in[6];  const float* t_b1 = (const float*)d_in[7];
  const float* t_w2 = (const float*)d_in[8];  const float* t_b2 = (const float*)d_in[9];
  const float* wq   = (const float*)d_in[10]; const float* bq   = (const float*)d_in[11];
  const float* wk   = (const float*)d_in[12]; const float* bk   = (const float*)d_in[13];
  const float* wv   = (const float*)d_in[14]; const float* bv   = (const float*)d_in[15];
  const float* wo   = (const float*)d_in[16]; const float* bo   = (const float*)d_in[17];
  const float* a_w1 = (const float*)d_in[18]; const float* a_b1 = (const float*)d_in[19];
  const float* a_w2 = (const float*)d_in[20]; const float* a_b2 = (const float*)d_in[21];
  const float* a_w3 = (const float*)d_in[22]; const float* a_b3 = (const float*)d_in[23];

  float* wsf   = (float*)d_ws;
  float* kbuf  = wsf;                                   // 32*512*64
  float* vbuf  = kbuf  + (size_t)NB * NR * 64;          // 32*512*64
  float* rpbuf = vbuf  + (size_t)NB * NR * 64;          // 32*512*64
  float* qbuf  = rpbuf + (size_t)NB * NR * 64;          // 32*128*64
  unsigned short* w2f = (unsigned short*)(qbuf + (size_t)NB * NT * 64); // 8*64*8
  float* wfuse = (float*)(w2f + 8 * 64 * 8);            // 64*64
  float* bfuse = wfuse + 64 * 64;                       // 64

  enc_kernel<<<dim3(641), dim3(256), 0, stream>>>(
      rs, ts, r_w1, r_b1, r_w2, r_b2, t_w1, t_b1, t_w2, t_b2,
      wq, bq, wk, bk, wv, bv, a_w1, a_w2, wo, bo, a_b1,
      kbuf, vbuf, rpbuf, qbuf, w2f, wfuse, bfuse);

  attn_pair_kernel<<<dim3(2048), dim3(256), 0, stream>>>(
      qbuf, kbuf, vbuf, wfuse, bfuse, w2f, a_b2, a_w3, rpbuf,
      (float*)d_out);
}

// Round 8
// 193.074 us; speedup vs baseline: 1.0164x; 1.0164x over previous
//
#include <hip/hip_runtime.h>
#include <hip/hip_bf16.h>
#include <math.h>

#define NB 32
#define NR 512
#define NT 128

typedef __attribute__((ext_vector_type(8))) short short8;
typedef __attribute__((ext_vector_type(4))) float f32x4;
typedef __attribute__((ext_vector_type(2))) float f32x2;

// ---------------- wave (64-lane) reductions ----------------
#define DPPF(s, ctrl) \
  __int_as_float(__builtin_amdgcn_update_dpp(0, __float_as_int(s), ctrl, 0xf, 0xf, true))

__device__ __forceinline__ float wred_max(float v){
  v = fmaxf(v, DPPF(v, 0xB1));
  v = fmaxf(v, DPPF(v, 0x4E));
  v = fmaxf(v, DPPF(v, 0x141));
  v = fmaxf(v, DPPF(v, 0x140));
  v = fmaxf(v, __shfl_xor(v, 16));
  v = fmaxf(v, __shfl_xor(v, 32));
  return v;
}
__device__ __forceinline__ float wred_sum(float v){
  v += DPPF(v, 0xB1);
  v += DPPF(v, 0x4E);
  v += DPPF(v, 0x141);
  v += DPPF(v, 0x140);
  v += __shfl_xor(v, 16);
  v += __shfl_xor(v, 32);
  return v;
}

// packed (f32x2) variants: 2 values per op via v_pk_*
__device__ __forceinline__ f32x2 wred_max2(f32x2 v){
  f32x2 t;
  t.x = DPPF(v.x, 0xB1);  t.y = DPPF(v.y, 0xB1);  v = __builtin_elementwise_max(v, t);
  t.x = DPPF(v.x, 0x4E);  t.y = DPPF(v.y, 0x4E);  v = __builtin_elementwise_max(v, t);
  t.x = DPPF(v.x, 0x141); t.y = DPPF(v.y, 0x141); v = __builtin_elementwise_max(v, t);
  t.x = DPPF(v.x, 0x140); t.y = DPPF(v.y, 0x140); v = __builtin_elementwise_max(v, t);
  t.x = __shfl_xor(v.x, 16); t.y = __shfl_xor(v.y, 16); v = __builtin_elementwise_max(v, t);
  t.x = __shfl_xor(v.x, 32); t.y = __shfl_xor(v.y, 32); v = __builtin_elementwise_max(v, t);
  return v;
}
__device__ __forceinline__ f32x2 wred_sum2(f32x2 v){
  f32x2 t;
  t.x = DPPF(v.x, 0xB1);  t.y = DPPF(v.y, 0xB1);  v += t;
  t.x = DPPF(v.x, 0x4E);  t.y = DPPF(v.y, 0x4E);  v += t;
  t.x = DPPF(v.x, 0x141); t.y = DPPF(v.y, 0x141); v += t;
  t.x = DPPF(v.x, 0x140); t.y = DPPF(v.y, 0x140); v += t;
  t.x = __shfl_xor(v.x, 16); t.y = __shfl_xor(v.y, 16); v += t;
  t.x = __shfl_xor(v.x, 32); t.y = __shfl_xor(v.y, 32); v += t;
  return v;
}

// packed 16-lane-group sum (2 robots per chain). Result in n16==15.
__device__ __forceinline__ f32x2 dpp_add16_pk(f32x2 s){
  f32x2 t;
  t.x = DPPF(s.x, 0x111); t.y = DPPF(s.y, 0x111); s += t;   // row_shr:1
  t.x = DPPF(s.x, 0x112); t.y = DPPF(s.y, 0x112); s += t;   // row_shr:2
  t.x = DPPF(s.x, 0x114); t.y = DPPF(s.y, 0x114); s += t;   // row_shr:4
  t.x = DPPF(s.x, 0x118); t.y = DPPF(s.y, 0x118); s += t;   // row_shr:8
  return s;
}

// ---------------- encoder kernel (641 blocks, unchanged) ----------------
__global__ __launch_bounds__(256) void enc_kernel(
    const float* __restrict__ rs, const float* __restrict__ ts,
    const float* __restrict__ r_w1, const float* __restrict__ r_b1,
    const float* __restrict__ r_w2, const float* __restrict__ r_b2,
    const float* __restrict__ t_w1, const float* __restrict__ t_b1,
    const float* __restrict__ t_w2, const float* __restrict__ t_b2,
    const float* __restrict__ wq, const float* __restrict__ bq,
    const float* __restrict__ wk, const float* __restrict__ bk,
    const float* __restrict__ wv, const float* __restrict__ bv,
    const float* __restrict__ a_w1, const float* __restrict__ a_w2,
    const float* __restrict__ wo, const float* __restrict__ bo,
    const float* __restrict__ a_b1,
    float* __restrict__ kbuf, float* __restrict__ vbuf,
    float* __restrict__ rpbuf, float* __restrict__ qbuf,
    unsigned short* __restrict__ w2f,
    float* __restrict__ wfuse, float* __restrict__ bfuse)
{
  __shared__ float w1s[448];
  __shared__ float wss[4096];
  __shared__ float h_s[32 * 66];
  __shared__ float rf_s[32 * 66];

  const int tid = threadIdx.x;
  const int blk = blockIdx.x;

  if (blk == 640) {        // fused prep block
#pragma unroll
    for (int c = 0; c < 4; ++c)
      ((float4*)wss)[c * 256 + tid] = ((const float4*)wo)[c * 256 + tid];

    // split a_w2 into hi/lo bf16 B-frags
    if (tid < 64) {
      int l = tid, n16 = l & 15, g = l >> 4;
      for (int f = 0; f < 8; ++f) {
        int ntile = f & 1, ks = (f >> 1) & 1, part = f >> 2;
        for (int j = 0; j < 8; ++j) {
          int k = ks * 32 + g * 8 + j;
          int n = ntile * 16 + n16;
          unsigned wb = __float_as_uint(a_w2[k * 32 + n]);
          unsigned hib = wb & 0xffff0000u;
          float lof = __uint_as_float(wb) - __uint_as_float(hib);
          unsigned lob = __float_as_uint(lof) & 0xffff0000u;
          w2f[((size_t)f * 64 + l) * 8 + j] =
              (unsigned short)((part == 0 ? hib : lob) >> 16);
        }
      }
    }
    __syncthreads();

    // wfuse = wo @ a_w1[:64]  (64x64) -- D/E linear collapse (no relu between)
    {
      const int j = tid & 63, kg = tid >> 6;
      float acc[16];
#pragma unroll
      for (int kk = 0; kk < 16; ++kk) acc[kk] = 0.f;
      for (int m = 0; m < 64; ++m) {
        float aw = a_w1[m * 64 + j];
#pragma unroll
        for (int kk = 0; kk < 16; ++kk)
          acc[kk] += wss[(kg * 16 + kk) * 64 + m] * aw;
      }
#pragma unroll
      for (int kk = 0; kk < 16; ++kk)
        wfuse[(kg * 16 + kk) * 64 + j] = acc[kk];
    }
    // bfuse = bo @ a_w1[:64] + a_b1
    if (tid < 64) {
      float acc = a_b1[tid];
      for (int m = 0; m < 64; ++m) acc += bo[m] * a_w1[m * 64 + tid];
      bfuse[tid] = acc;
    }
    return;
  }

  const int rb = tid >> 3, t8 = tid & 7;
  const bool robot = blk < 512;

  if (robot) {
    if (tid < 112) ((float4*)w1s)[tid] = ((const float4*)r_w1)[tid];
#pragma unroll
    for (int c = 0; c < 4; ++c)
      ((float4*)wss)[c * 256 + tid] = ((const float4*)r_w2)[c * 256 + tid];
  } else {
    if (tid < 96) ((float4*)w1s)[tid] = ((const float4*)t_w1)[tid];
#pragma unroll
    for (int c = 0; c < 4; ++c)
      ((float4*)wss)[c * 256 + tid] = ((const float4*)t_w2)[c * 256 + tid];
  }

  int g, K1;
  const float* xin; const float* b1; const float* b2;
  if (robot) { g = blk * 32 + rb;          K1 = 7; xin = rs + (size_t)g * 7; b1 = r_b1; b2 = r_b2; }
  else       { g = (blk - 512) * 32 + rb;  K1 = 6; xin = ts + (size_t)g * 6; b1 = t_b1; b2 = t_b2; }

  float x[7];
  for (int k = 0; k < K1; ++k) x[k] = xin[k];
  __syncthreads();

  {
    float acc[8];
#pragma unroll
    for (int jj = 0; jj < 8; ++jj) acc[jj] = b1[t8 * 8 + jj];
    for (int k = 0; k < K1; ++k) {
      float xv = x[k];
#pragma unroll
      for (int jj = 0; jj < 8; ++jj) acc[jj] += xv * w1s[k * 64 + t8 * 8 + jj];
    }
#pragma unroll
    for (int jj = 0; jj < 8; ++jj) h_s[rb * 66 + t8 * 8 + jj] = fmaxf(acc[jj], 0.f);
  }
  __syncthreads();

  {
    float acc[8];
#pragma unroll
    for (int jj = 0; jj < 8; ++jj) acc[jj] = b2[t8 * 8 + jj];
    for (int k = 0; k < 64; ++k) {
      float hv = h_s[rb * 66 + k];
      const float4* wr = (const float4*)(wss + k * 64 + t8 * 8);
#pragma unroll
      for (int j4 = 0; j4 < 2; ++j4) {
        float4 w = wr[j4];
        acc[j4 * 4 + 0] += hv * w.x; acc[j4 * 4 + 1] += hv * w.y;
        acc[j4 * 4 + 2] += hv * w.z; acc[j4 * 4 + 3] += hv * w.w;
      }
    }
#pragma unroll
    for (int jj = 0; jj < 8; ++jj) rf_s[rb * 66 + t8 * 8 + jj] = fmaxf(acc[jj], 0.f);
  }

  const float* wp[3]; const float* bp[3]; float* op[3]; int npass;
  if (robot) {
    wp[0] = wk; bp[0] = bk;      op[0] = kbuf;
    wp[1] = wv; bp[1] = bv;      op[1] = vbuf;
    wp[2] = a_w1 + 64 * 64; bp[2] = nullptr; op[2] = rpbuf;
    npass = 3;
  } else {
    wp[0] = wq; bp[0] = bq; op[0] = qbuf; npass = 1;
  }
  for (int p = 0; p < npass; ++p) {
    __syncthreads();
#pragma unroll
    for (int c = 0; c < 4; ++c)
      ((float4*)wss)[c * 256 + tid] = ((const float4*)wp[p])[c * 256 + tid];
    __syncthreads();
    float acc[8];
#pragma unroll
    for (int jj = 0; jj < 8; ++jj) acc[jj] = bp[p] ? bp[p][t8 * 8 + jj] : 0.f;
    for (int k = 0; k < 64; ++k) {
      float hv = rf_s[rb * 66 + k];
      const float4* wr = (const float4*)(wss + k * 64 + t8 * 8);
#pragma unroll
      for (int j4 = 0; j4 < 2; ++j4) {
        float4 w = wr[j4];
        acc[j4 * 4 + 0] += hv * w.x; acc[j4 * 4 + 1] += hv * w.y;
        acc[j4 * 4 + 2] += hv * w.z; acc[j4 * 4 + 3] += hv * w.w;
      }
    }
    float4* o4 = (float4*)(op[p] + (size_t)g * 64 + t8 * 8);
    o4[0] = make_float4(acc[0], acc[1], acc[2], acc[3]);
    o4[1] = make_float4(acc[4], acc[5], acc[6], acc[7]);
  }
}

// ---------------- split helpers (pair) -------------------------------------
// NOTE (R7 lesson): keep the HIP software RNE conversion here. Replacing it
// with inline-asm v_cvt_pk_bf16_f32 removed ~15% of VALU issues but ADDED
// ~18 us of exposed stalls (81.4 -> 91 us): the conversion arithmetic was
// hiding under MFMA latency, and opaque asm blocks the scheduler from
// interleaving it. Do not "optimize" this with asm again.
__device__ __forceinline__ void mk2(f32x2 r, f32x2 t,
                                    unsigned* h, unsigned* l)
{
  f32x2 x = r + t;
  x = __builtin_elementwise_max(x, (f32x2){0.f, 0.f});
  __hip_bfloat162 hb = __float22bfloat162_rn(make_float2(x.x, x.y));
  unsigned hh; __builtin_memcpy(&hh, &hb, 4);
  f32x2 hf;
  hf.x = __int_as_float((int)(hh << 16));
  hf.y = __int_as_float((int)(hh & 0xffff0000u));
  f32x2 e = x - hf;
  __hip_bfloat162 lb = __float22bfloat162_rn(make_float2(e.x, e.y));
  unsigned ll; __builtin_memcpy(&ll, &lb, 4);
  *h = hh; *l = ll;
}

__device__ __forceinline__ void mk_frags(float4 ra, float4 rb,
                                         float4 ta, float4 tb,
                                         short8* Ah, short8* Al)
{
  unsigned h0, h1, h2, h3, l0, l1, l2, l3;
  mk2((f32x2){ra.x, ra.y}, (f32x2){ta.x, ta.y}, &h0, &l0);
  mk2((f32x2){ra.z, ra.w}, (f32x2){ta.z, ta.w}, &h1, &l1);
  mk2((f32x2){rb.x, rb.y}, (f32x2){tb.x, tb.y}, &h2, &l2);
  mk2((f32x2){rb.z, rb.w}, (f32x2){tb.z, tb.w}, &h3, &l3);
  *Ah = __builtin_bit_cast(short8, make_int4((int)h0, (int)h1, (int)h2, (int)h3));
  *Al = __builtin_bit_cast(short8, make_int4((int)l0, (int)l1, (int)l2, (int)l3));
}

// ---------------- fused attention + pairwise kernel ------------------------
// v14 = v12 exact revert (session-best: 81.4 us attn, no spills, 64 VGPR).
// R7's asm-cvt + LDS-alias experiment regressed (see mk2 note); banked best.
__global__ __launch_bounds__(256, 4) void attn_pair_kernel(
    const float* __restrict__ qbuf, const float* __restrict__ kbuf,
    const float* __restrict__ vbuf,
    const float* __restrict__ wfuse, const float* __restrict__ bfuse,
    const unsigned short* __restrict__ w2f,
    const float* __restrict__ a_b2, const float* __restrict__ a_w3,
    const float* __restrict__ rpbuf,
    float* __restrict__ out)
{
  __shared__ float qt_s[2 * 64];        // q in phase A
  __shared__ float lg[4160];            // p pairs A-C; ctx partials; scores
  __shared__ float inv_s[8];
  __shared__ float cp[4][2 * 64];
  __shared__ float ctx_s[2 * 64];
  __shared__ float tp_f[2 * 64];
  __shared__ float red_a[4];
  __shared__ float red_b[4];

  float* const lgf = lg;

  const int tid = threadIdx.x;
  const int jj = blockIdx.x & 31;
  const int b  = (jj & 7) * 4 + (jj >> 3);   // XCD-locality swizzle
  const int t0 = (blockIdx.x >> 5) * 2;      // 64 task-pairs

  // ---------- attn phase A: logits ----------
  if (tid < 32) {
    int tt = tid >> 4, i4 = tid & 15;
    float4 v = ((const float4*)(qbuf + (size_t)(b * NT + t0 + tt) * 64))[i4];
    v.x *= 0.25f; v.y *= 0.25f; v.z *= 0.25f; v.w *= 0.25f;   // 1/sqrt(16)
    ((float4*)qt_s)[tid] = v;
  }
  __syncthreads();

  {
    const int h = tid & 3;
    const int r0 = tid >> 2;
    const f32x4* q0p = (const f32x4*)(qt_s + h * 16);
    const f32x4* q1p = (const f32x4*)(qt_s + 64 + h * 16);
    f32x2 q0[8], q1[8];
#pragma unroll
    for (int j = 0; j < 4; ++j) {
      f32x4 a = q0p[j], c = q1p[j];
      q0[2 * j]     = __builtin_shufflevector(a, a, 0, 1);
      q0[2 * j + 1] = __builtin_shufflevector(a, a, 2, 3);
      q1[2 * j]     = __builtin_shufflevector(c, c, 0, 1);
      q1[2 * j + 1] = __builtin_shufflevector(c, c, 2, 3);
    }
    const float* kb0 = kbuf + (size_t)b * NR * 64 + h * 16;
    for (int it = 0; it < 8; ++it) {
      int r = r0 + it * 64;
      const f32x4* k4 = (const f32x4*)(kb0 + (size_t)r * 64);
      f32x2 a0 = {0.f, 0.f}, a1 = {0.f, 0.f};
#pragma unroll
      for (int j = 0; j < 4; ++j) {
        f32x4 kv = k4[j];
        f32x2 kl = __builtin_shufflevector(kv, kv, 0, 1);
        f32x2 kh = __builtin_shufflevector(kv, kv, 2, 3);
        a0 = __builtin_elementwise_fma(kl, q0[2 * j], a0);
        a0 = __builtin_elementwise_fma(kh, q0[2 * j + 1], a0);
        a1 = __builtin_elementwise_fma(kl, q1[2 * j], a1);
        a1 = __builtin_elementwise_fma(kh, q1[2 * j + 1], a1);
      }
      *(f32x2*)(lgf + h * 1040 + r * 2) = (f32x2){a0.x + a0.y, a1.x + a1.y};
    }
  }
  __syncthreads();

  // ---------- attn phase B: softmax, both tasks per row (packed) ----------
  {
    const int hh = tid >> 6, lane = tid & 63;
    float* row = lgf + hh * 1040;
    f32x2 v0[8];
#pragma unroll
    for (int u = 0; u < 8; ++u) v0[u] = *(const f32x2*)(row + (u * 64 + lane) * 2);
    f32x2 m = v0[0];
#pragma unroll
    for (int u = 1; u < 8; ++u) m = __builtin_elementwise_max(m, v0[u]);
    m = wred_max2(m);
    f32x2 s = {0.f, 0.f};
#pragma unroll
    for (int u = 0; u < 8; ++u) {
      f32x2 e;
      e.x = __expf(v0[u].x - m.x);
      e.y = __expf(v0[u].y - m.y);
      *(f32x2*)(row + (u * 64 + lane) * 2) = e;
      s += e;
    }
    s = wred_sum2(s);
    if (lane == 0) {
      inv_s[hh]     = __builtin_amdgcn_rcpf(s.x);
      inv_s[4 + hh] = __builtin_amdgcn_rcpf(s.y);
    }
  }
  __syncthreads();

  // ---------- attn phase C: ctx = p.v (b128 p-pairs, pk-FMA) ----------
  {
    const int dg = tid & 15, rc = tid >> 4;
    const int h = dg >> 2;
    const float* vptr = vbuf + (size_t)b * NR * 64 + dg * 4;
    const float* pr = lgf + h * 1040 + rc * 64;     // r = rc*32 + i
    f32x4 acc0 = {0.f, 0.f, 0.f, 0.f}, acc1 = {0.f, 0.f, 0.f, 0.f};
#pragma unroll 8
    for (int i = 0; i < 32; i += 2) {
      int r = rc * 32 + i;
      f32x4 vv0 = *(const f32x4*)(vptr + (size_t)r * 64);
      f32x4 vv1 = *(const f32x4*)(vptr + (size_t)(r + 1) * 64);
      f32x4 pp = *(const f32x4*)(pr + i * 2);        // p0[i],p1[i],p0[i+1],p1[i+1]
      acc0 = __builtin_elementwise_fma(vv0, (f32x4){pp.x, pp.x, pp.x, pp.x}, acc0);
      acc1 = __builtin_elementwise_fma(vv0, (f32x4){pp.y, pp.y, pp.y, pp.y}, acc1);
      acc0 = __builtin_elementwise_fma(vv1, (f32x4){pp.z, pp.z, pp.z, pp.z}, acc0);
      acc1 = __builtin_elementwise_fma(vv1, (f32x4){pp.w, pp.w, pp.w, pp.w}, acc1);
    }
    __syncthreads();                               // all p reads complete
    *(f32x4*)(lgf + rc * 132 + dg * 4)      = acc0;
    *(f32x4*)(lgf + rc * 132 + 64 + dg * 4) = acc1;
  }
  __syncthreads();
  if (tid < 128) {
    float s = 0.f;
#pragma unroll
    for (int rc = 0; rc < 16; ++rc) s += lgf[rc * 132 + tid];
    ctx_s[tid] = s * inv_s[(tid >> 6) * 4 + ((tid & 63) >> 4)];
  }
  __syncthreads();

  // ---------- fused D+E: tp = ctx @ wfuse + bfuse ----------
  {
    int jd = tid & 63, kc = tid >> 6;
    float p0 = 0.f, p1 = 0.f;
    for (int k = 0; k < 16; ++k) {
      float w = wfuse[(kc * 16 + k) * 64 + jd];
      p0 += ctx_s[kc * 16 + k] * w;
      p1 += ctx_s[64 + kc * 16 + k] * w;
    }
    cp[kc][jd]      = p0;
    cp[kc][64 + jd] = p1;
  }
  __syncthreads();
  if (tid < 128) {
    int jd = tid & 63;
    tp_f[tid] = cp[0][tid] + cp[1][tid] + cp[2][tid] + cp[3][tid] + bfuse[jd];
  }
  __syncthreads();

  // ---------- pair body (MFMA sequence; packed epilogue) ----------
  const int wave = tid >> 6, lane = tid & 63;
  const int n16 = lane & 15, g = lane >> 4;

  short8 B[8];
#pragma unroll
  for (int f = 0; f < 8; ++f)
    B[f] = __builtin_bit_cast(short8, ((const int4*)w2f)[f * 64 + lane]);

  const float* tpA = tp_f + g * 8;
  const float* tpB = tp_f + 64 + g * 8;
  float4 tA0a = *(const float4*)(tpA),      tA0b = *(const float4*)(tpA + 4);
  float4 tA1a = *(const float4*)(tpA + 32), tA1b = *(const float4*)(tpA + 36);
  float4 tB0a = *(const float4*)(tpB),      tB0b = *(const float4*)(tpB + 4);
  float4 tB1a = *(const float4*)(tpB + 32), tB1b = *(const float4*)(tpB + 36);

  float b20 = a_b2[n16], b21 = a_b2[16 + n16];
  float w30 = a_w3[n16], w31 = a_w3[16 + n16];

  const float* rpb = rpbuf + (size_t)b * NR * 64 + g * 8;

  const float4* rp0 = (const float4*)(rpb + (size_t)(wave * 128 + n16) * 64);
  float4 ra0 = rp0[0], rb0 = rp0[1], ra1 = rp0[8], rb1 = rp0[9];

#pragma unroll
  for (int mt = 0; mt < 8; ++mt) {
    float4 na0, nb0, na1, nb1;
    if (mt < 7) {
      const float4* rpn =
          (const float4*)(rpb + (size_t)(wave * 128 + (mt + 1) * 16 + n16) * 64);
      na0 = rpn[0]; nb0 = rpn[1]; na1 = rpn[8]; nb1 = rpn[9];
    }

#pragma unroll
    for (int task = 0; task < 2; ++task) {
      short8 Ah0, Al0, Ah1, Al1;
      if (task == 0) {
        mk_frags(ra0, rb0, tA0a, tA0b, &Ah0, &Al0);
        mk_frags(ra1, rb1, tA1a, tA1b, &Ah1, &Al1);
      } else {
        mk_frags(ra0, rb0, tB0a, tB0b, &Ah0, &Al0);
        mk_frags(ra1, rb1, tB1a, tB1b, &Ah1, &Al1);
      }
      f32x4 acc0 = (f32x4){b20, b20, b20, b20};
      f32x4 acc1 = (f32x4){b21, b21, b21, b21};
      acc0 = __builtin_amdgcn_mfma_f32_16x16x32_bf16(Ah0, B[0], acc0, 0, 0, 0);
      acc1 = __builtin_amdgcn_mfma_f32_16x16x32_bf16(Ah0, B[1], acc1, 0, 0, 0);
      acc0 = __builtin_amdgcn_mfma_f32_16x16x32_bf16(Al0, B[0], acc0, 0, 0, 0);
      acc1 = __builtin_amdgcn_mfma_f32_16x16x32_bf16(Al0, B[1], acc1, 0, 0, 0);
      acc0 = __builtin_amdgcn_mfma_f32_16x16x32_bf16(Ah0, B[4], acc0, 0, 0, 0);
      acc1 = __builtin_amdgcn_mfma_f32_16x16x32_bf16(Ah0, B[5], acc1, 0, 0, 0);
      acc0 = __builtin_amdgcn_mfma_f32_16x16x32_bf16(Ah1, B[2], acc0, 0, 0, 0);
      acc1 = __builtin_amdgcn_mfma_f32_16x16x32_bf16(Ah1, B[3], acc1, 0, 0, 0);
      acc0 = __builtin_amdgcn_mfma_f32_16x16x32_bf16(Al1, B[2], acc0, 0, 0, 0);
      acc1 = __builtin_amdgcn_mfma_f32_16x16x32_bf16(Al1, B[3], acc1, 0, 0, 0);
      acc0 = __builtin_amdgcn_mfma_f32_16x16x32_bf16(Ah1, B[6], acc0, 0, 0, 0);
      acc1 = __builtin_amdgcn_mfma_f32_16x16x32_bf16(Ah1, B[7], acc1, 0, 0, 0);
      // packed epilogue: robots (reg0,reg1) and (reg2,reg3) as f32x2
      {
        f32x2 z = {0.f, 0.f};
        f32x2 w30v = {w30, w30}, w31v = {w31, w31};
        f32x2 m01 = __builtin_elementwise_max(
            (f32x2){acc0[0], acc0[1]}, z);
        f32x2 m23 = __builtin_elementwise_max(
            (f32x2){acc0[2], acc0[3]}, z);
        f32x2 n01 = __builtin_elementwise_max(
            (f32x2){acc1[0], acc1[1]}, z);
        f32x2 n23 = __builtin_elementwise_max(
            (f32x2){acc1[2], acc1[3]}, z);
        f32x2 s01 = __builtin_elementwise_fma(n01, w31v, m01 * w30v);
        f32x2 s23 = __builtin_elementwise_fma(n23, w31v, m23 * w30v);
        s01 = dpp_add16_pk(s01);
        s23 = dpp_add16_pk(s23);
        if (n16 == 15) {
          float* dst = lgf + task * 512 + wave * 128 + mt * 16 + g * 4;
          *(f32x2*)(dst)     = s01;
          *(f32x2*)(dst + 2) = s23;
        }
      }
    }
    ra0 = na0; rb0 = nb0; ra1 = na1; rb1 = nb1;
  }
  __syncthreads();

  // ---------- softmax over 512 robots, 128 threads per task ----------
  {
    const int task = tid >> 7, t2 = tid & 127;
    const int lw = tid & 63, wid = tid >> 6;
    const float* pp = lgf + task * 512;
    float v0 = pp[t2], v1 = pp[t2 + 128], v2 = pp[t2 + 256], v3 = pp[t2 + 384];
    float m = wred_max(fmaxf(fmaxf(v0, v1), fmaxf(v2, v3)));
    if (lw == 0) red_a[wid] = m;
    __syncthreads();
    m = fmaxf(red_a[task * 2], red_a[task * 2 + 1]);
    float e0 = __expf(v0 - m), e1 = __expf(v1 - m);
    float e2 = __expf(v2 - m), e3 = __expf(v3 - m);
    float ss = wred_sum((e0 + e1) + (e2 + e3));
    if (lw == 0) red_b[wid] = ss;
    __syncthreads();
    float inv = __builtin_amdgcn_rcpf(red_b[task * 2] + red_b[task * 2 + 1]);
    float* op = out + (size_t)(b * NT + t0 + task) * NR;
    op[t2]       = e0 * inv;
    op[t2 + 128] = e1 * inv;
    op[t2 + 256] = e2 * inv;
    op[t2 + 384] = e3 * inv;
  }
}

// ---------------- launch ----------------
extern "C" void kernel_launch(void* const* d_in, const int* in_sizes, int n_in,
                              void* d_out, int out_size, void* d_ws, size_t ws_size,
                              hipStream_t stream)
{
  const float* rs   = (const float*)d_in[0];
  const float* ts   = (const float*)d_in[1];
  const float* r_w1 = (const float*)d_in[2];  const float* r_b1 = (const float*)d_in[3];
  const float* r_w2 = (const float*)d_in[4];  const float* r_b2 = (const float*)d_in[5];
  const float* t_w1 = (const float*)d_in[6];  const float* t_b1 = (const float*)d_in[7];
  const float* t_w2 = (const float*)d_in[8];  const float* t_b2 = (const float*)d_in[9];
  const float* wq   = (const float*)d_in[10]; const float* bq   = (const float*)d_in[11];
  const float* wk   = (const float*)d_in[12]; const float* bk   = (const float*)d_in[13];
  const float* wv   = (const float*)d_in[14]; const float* bv   = (const float*)d_in[15];
  const float* wo   = (const float*)d_in[16]; const float* bo   = (const float*)d_in[17];
  const float* a_w1 = (const float*)d_in[18]; const float* a_b1 = (const float*)d_in[19];
  const float* a_w2 = (const float*)d_in[20]; const float* a_b2 = (const float*)d_in[21];
  const float* a_w3 = (const float*)d_in[22]; const float* a_b3 = (const float*)d_in[23];

  float* wsf   = (float*)d_ws;
  float* kbuf  = wsf;                                   // 32*512*64
  float* vbuf  = kbuf  + (size_t)NB * NR * 64;          // 32*512*64
  float* rpbuf = vbuf  + (size_t)NB * NR * 64;          // 32*512*64
  float* qbuf  = rpbuf + (size_t)NB * NR * 64;          // 32*128*64
  unsigned short* w2f = (unsigned short*)(qbuf + (size_t)NB * NT * 64); // 8*64*8
  float* wfuse = (float*)(w2f + 8 * 64 * 8);            // 64*64
  float* bfuse = wfuse + 64 * 64;                       // 64

  enc_kernel<<<dim3(641), dim3(256), 0, stream>>>(
      rs, ts, r_w1, r_b1, r_w2, r_b2, t_w1, t_b1, t_w2, t_b2,
      wq, bq, wk, bk, wv, bv, a_w1, a_w2, wo, bo, a_b1,
      kbuf, vbuf, rpbuf, qbuf, w2f, wfuse, bfuse);

  attn_pair_kernel<<<dim3(2048), dim3(256), 0, stream>>>(
      qbuf, kbuf, vbuf, wfuse, bfuse, w2f, a_b2, a_w3, rpbuf,
      (float*)d_out);
}